// Round 1
// baseline (493.239 us; speedup 1.0000x reference)
//
#include <hip/hip_runtime.h>
#include <stdint.h>

// ---------------------------------------------------------------------------
// scores[b,s] = v . tanh( hidden[b] @ Wh + bias + enc[s,b] @ We )
// out[b,s]   = softmax_s(scores)
// Big GEMM: enc_flat[M=65536,K=1024] @ We[K=1024,N=512], bf16 MFMA.
// R3: latency fix. global_load_lds + __syncthreads forced a vmcnt(0) drain
//     every 32-k phase (~900cy exposed x 32 phases, 2 waves/SIMD -> idle).
//     Now: reg-staged A (global fp32 -> VGPR, issued 3 phases ahead),
//     single fp32->bf16 convert at stage time (was 4x redundant per-wave),
//     bf16 LDS double buffer (4KB each, conflict-minimal layout).
//     Barriers no longer drain vmcnt; loads ride across them (T14/T3 style).
// ---------------------------------------------------------------------------

typedef float  floatx4 __attribute__((ext_vector_type(4)));
typedef __bf16 bf16x8  __attribute__((ext_vector_type(8)));
typedef short  short8  __attribute__((ext_vector_type(8)));

union bfu { bf16x8 v; short8 s; };

#define LOG2E_X2 2.8853900817779268f

// ---- kernel 0: W[512:1536,:] -> bf16 transposed Wt[n][k], LDS-tiled 64x64.
__global__ void wt_convert(const float* __restrict__ W, __bf16* __restrict__ Wt) {
  __shared__ float tile[64][65];                 // +1 pad: conflict-free both ways
  const int kt = blockIdx.x >> 3;                // 16 k-tiles
  const int nt = blockIdx.x & 7;                 // 8 n-tiles
  const int c  = threadIdx.x & 63;
  const int r4 = threadIdx.x >> 6;               // 4 rows per pass
  #pragma unroll 4
  for (int i = 0; i < 16; i++) {
    int r = i * 4 + r4;                          // k-local
    tile[r][c] = W[(long)(512 + kt * 64 + r) * 512 + nt * 64 + c];
  }
  __syncthreads();
  #pragma unroll 4
  for (int i = 0; i < 16; i++) {
    int n = i * 4 + r4;                          // n-local; lane c = k-local
    Wt[(long)(nt * 64 + n) * 1024 + kt * 64 + c] = (__bf16)tile[c][n];
  }
}

// ---- kernel 1: hproj[b][n] = bias[n] + sum_k hidden[b,k] * W[k,n]  (k<512)
__global__ void hproj_kernel(const float* __restrict__ hidden,
                             const float* __restrict__ W,
                             const float* __restrict__ bias,
                             float* __restrict__ hproj) {
  const int tid = threadIdx.x;            // n
  const int b_  = blockIdx.x >> 2;
  const int kc  = blockIdx.x & 3;
  __shared__ float hid[128];
  if (tid < 128) hid[tid] = hidden[b_ * 512 + kc * 128 + tid];
  __syncthreads();
  float acc = (kc == 0) ? bias[tid] : 0.f;
  const float* Wp = W + (long)(kc * 128) * 512 + tid;
  #pragma unroll 8
  for (int k = 0; k < 128; k++) acc = fmaf(hid[k], Wp[(long)k * 512], acc);
  atomicAdd(&hproj[b_ * 512 + tid], acc);
}

// ---- kernel 2: the big GEMM + tanh/v-dot epilogue, reg-staged pipeline
__global__ __launch_bounds__(256, 2) void gemm_score(
    const float* __restrict__ enc,    // [65536][1024] fp32
    const __bf16* __restrict__ Wt,    // [512][1024] bf16 (n-major)
    const float* __restrict__ hproj,  // [64][512]
    const float* __restrict__ v,      // [512]
    float* __restrict__ scores)       // [64][1024]  ([b][s])
{
  // bf16 A tile, double buffered. elem layout: [c][m][j], c=k/8, j=k%8
  // addr = c*512 + m*8 + j  (c in 0..3, m in 0..63, j in 0..7) -> 4KB/buffer
  __shared__ __bf16 ldsA[2][2048];
  __shared__ float bscore[64];

  const int tid  = threadIdx.x;
  const int lane = tid & 63;
  const int wv   = tid >> 6;      // wave -> n-range [wv*128, wv*128+128)
  const int q    = lane >> 4;
  const int t    = lane & 15;
  const long m0  = (long)blockIdx.x * 64;

  // staging coords: thread -> row sm = tid>>2, k-chunk sf = tid&3; 32B/thread
  const int sm = tid >> 2;
  const int sf = tid & 3;
  const float* ap = enc + (m0 + sm) * 1024 + sf * 8;
  __bf16* aw0 = &ldsA[0][sf * 512 + sm * 8];   // ds_write_b128 dest (16B)
  __bf16* aw1 = &ldsA[1][sf * 512 + sm * 8];

  // fragment read base: lane (q,t) rt -> A[rt*16+t][q*8 .. q*8+7]
  const __bf16* ar0 = &ldsA[0][q * 512 + t * 8];
  const __bf16* ar1 = &ldsA[1][q * 512 + t * 8];

  // per-lane B base: Wt[n = wv*128 + ct*16 + t][k0 + q*8 ...], 16B per load
  const __bf16* bp = Wt + (long)(wv * 128 + t) * 1024 + q * 8;

  if (tid < 64) bscore[tid] = 0.f;

  floatx4 acc[4][8];
  #pragma unroll
  for (int i = 0; i < 4; i++)
    #pragma unroll
    for (int j = 0; j < 8; j++)
      acc[i][j] = (floatx4){0.f, 0.f, 0.f, 0.f};

  floatx4 ra[3][2];    // A staging regs: 3 k-steps in flight
  short8  bfr[2][8];   // B fragments, double buffered

  auto issueA = [&](int T, int s) {          // global fp32 -> regs (no wait)
    const float* p = ap + T * 32;
    ra[s][0] = *(const floatx4*)(p);
    ra[s][1] = *(const floatx4*)(p + 4);
  };
  auto writeA = [&](int s, __bf16* dst) {    // cvt once + 16B ds_write
    union bfu u;
    #pragma unroll
    for (int j = 0; j < 4; j++) {
      u.v[j]     = (__bf16)ra[s][0][j];
      u.v[4 + j] = (__bf16)ra[s][1][j];
    }
    *(bf16x8*)dst = u.v;
  };
  auto loadB = [&](int T, int s) {
    #pragma unroll
    for (int ct = 0; ct < 8; ct++) {
      union bfu u;
      u.v = *(const bf16x8*)(bp + T * 32 + (long)ct * 16 * 1024);
      bfr[s][ct] = u.s;
    }
  };
  auto compute = [&](const __bf16* base, int bs) {
    #pragma unroll
    for (int rt = 0; rt < 4; rt++) {
      union bfu u;
      u.v = *(const bf16x8*)(base + rt * 128);   // 1 ds_read_b128 per rt
      #pragma unroll
      for (int ct = 0; ct < 8; ct++)
        acc[rt][ct] = __builtin_amdgcn_mfma_f32_16x16x32_bf16(
            u.s, bfr[bs][ct], acc[rt][ct], 0, 0, 0);
    }
  };

  // prologue: A0..A2 in flight, B0/B1 in flight, stage A0 into buf0
  issueA(0, 0); issueA(1, 1); issueA(2, 2);
  loadB(0, 0);  loadB(1, 1);
  writeA(0, aw0);               // waits vmcnt for A0 only
  __syncthreads();              // no vmcnt drain: nothing targets LDS via vmem

  // Phase T: compute A(T) from buf(T&1) with B(T)=bfr[T&1];
  //   issue A(T+3) into set T%3 (freed: A(T) ds_written last phase, lgkm
  //   drained by that phase's barrier); cvt+write A(T+1) (loaded 2 phases
  //   ago -> vmcnt wait covered); reload B(T+2) after its MFMAs consumed it.
  // Macro-expanded so every ra[]/bfr[] index is a compile-time constant.
#define PHASE(T, SI, SW)                                   \
  {                                                        \
    if ((T) < 29) issueA((T) + 3, SI);                     \
    if ((T) < 31) writeA(SW, ((T) & 1) ? aw0 : aw1);       \
    compute(((T) & 1) ? ar1 : ar0, (T) & 1);               \
    if ((T) < 30) loadB((T) + 2, (T) & 1);                 \
    __syncthreads();                                       \
  }

  PHASE(0, 0, 1)  PHASE(1, 1, 2)  PHASE(2, 2, 0)  PHASE(3, 0, 1)
  PHASE(4, 1, 2)  PHASE(5, 2, 0)  PHASE(6, 0, 1)  PHASE(7, 1, 2)
  PHASE(8, 2, 0)  PHASE(9, 0, 1)  PHASE(10, 1, 2) PHASE(11, 2, 0)
  PHASE(12, 0, 1) PHASE(13, 1, 2) PHASE(14, 2, 0) PHASE(15, 0, 1)
  PHASE(16, 1, 2) PHASE(17, 2, 0) PHASE(18, 0, 1) PHASE(19, 1, 2)
  PHASE(20, 2, 0) PHASE(21, 0, 1) PHASE(22, 1, 2) PHASE(23, 2, 0)
  PHASE(24, 0, 1) PHASE(25, 1, 2) PHASE(26, 2, 0) PHASE(27, 0, 1)
  PHASE(28, 1, 2) PHASE(29, 2, 0) PHASE(30, 0, 1) PHASE(31, 1, 2)
#undef PHASE

  // ---- epilogue: score[row] = sum_n v[n] * tanh(acc + hproj[row][n])
  float vv[8];
  #pragma unroll
  for (int ct = 0; ct < 8; ct++) vv[ct] = v[wv * 128 + ct * 16 + t];

  #pragma unroll
  for (int rt = 0; rt < 4; rt++) {
    #pragma unroll
    for (int r = 0; r < 4; r++) {
      int row = rt * 16 + q * 4 + r;              // C/D: row=(lane>>4)*4+reg
      const float* hrow = hproj + row * 512 + wv * 128 + t;
      float s = 0.f;
      #pragma unroll
      for (int ct = 0; ct < 8; ct++) {
        float e  = acc[rt][ct][r] + hrow[ct * 16];
        float ex = __builtin_amdgcn_exp2f(e * LOG2E_X2);        // e^(2x)
        float th = 1.f - 2.f * __builtin_amdgcn_rcpf(ex + 1.f); // tanh(x)
        s = fmaf(vv[ct], th, s);
      }
      s += __shfl_xor(s, 1);
      s += __shfl_xor(s, 2);
      s += __shfl_xor(s, 4);
      s += __shfl_xor(s, 8);
      if (t == 0) atomicAdd(&bscore[row], s);
    }
  }
  __syncthreads();
  if (tid < 64) scores[(long)tid * 1024 + blockIdx.x] = bscore[tid];
}

// ---- kernel 3: softmax over s for each b
__global__ void softmax_kernel(const float* __restrict__ scores,
                               float* __restrict__ out) {
  const int b_   = blockIdx.x;
  const int tid  = threadIdx.x;
  const int lane = tid & 63;
  const int wv   = tid >> 6;
  __shared__ float redmax[4], redsum[4];

  float x[4];
  #pragma unroll
  for (int i = 0; i < 4; i++) x[i] = scores[b_ * 1024 + i * 256 + tid];
  float mx = fmaxf(fmaxf(x[0], x[1]), fmaxf(x[2], x[3]));
  #pragma unroll
  for (int off = 1; off < 64; off <<= 1) mx = fmaxf(mx, __shfl_xor(mx, off));
  if (lane == 0) redmax[wv] = mx;
  __syncthreads();
  mx = fmaxf(fmaxf(redmax[0], redmax[1]), fmaxf(redmax[2], redmax[3]));

  float e[4], s = 0.f;
  #pragma unroll
  for (int i = 0; i < 4; i++) { e[i] = __expf(x[i] - mx); s += e[i]; }
  #pragma unroll
  for (int off = 1; off < 64; off <<= 1) s += __shfl_xor(s, off);
  if (lane == 0) redsum[wv] = s;
  __syncthreads();
  s = redsum[0] + redsum[1] + redsum[2] + redsum[3];
  float inv = 1.f / s;
  #pragma unroll
  for (int i = 0; i < 4; i++) out[b_ * 1024 + i * 256 + tid] = e[i] * inv;
}

extern "C" void kernel_launch(void* const* d_in, const int* in_sizes, int n_in,
                              void* d_out, int out_size, void* d_ws, size_t ws_size,
                              hipStream_t stream) {
  (void)in_sizes; (void)n_in; (void)out_size; (void)ws_size;
  const float* hidden = (const float*)d_in[0];   // [64,512]
  const float* enc    = (const float*)d_in[1];   // [1024,64,1024]
  const float* W      = (const float*)d_in[2];   // [1536,512]
  const float* bias   = (const float*)d_in[3];   // [512]
  const float* v      = (const float*)d_in[4];   // [512]
  float* out = (float*)d_out;                    // [64,1024]

  char* ws = (char*)d_ws;
  __bf16* Wt    = (__bf16*)ws;                            // 1 MB
  float*  hproj = (float*)(ws + (1 << 20));               // 128 KB
  float*  scores= (float*)(ws + (1 << 20) + (128 << 10)); // 256 KB

  hipMemsetAsync(hproj, 0, 64 * 512 * sizeof(float), stream);
  wt_convert<<<128, 256, 0, stream>>>(W, Wt);
  hproj_kernel<<<256, 512, 0, stream>>>(hidden, W, bias, hproj);
  gemm_score<<<1024, 256, 0, stream>>>(enc, Wt, hproj, v, scores);
  softmax_kernel<<<64, 256, 0, stream>>>(scores, out);
}

// Round 2
// 469.009 us; speedup vs baseline: 1.0517x; 1.0517x over previous
//
#include <hip/hip_runtime.h>
#include <stdint.h>

// ---------------------------------------------------------------------------
// scores[b,s] = v . tanh( hidden[b] @ Wh + bias + enc[s,b] @ We )
// out[b,s]   = softmax_s(scores)
// Big GEMM: enc_flat[M=65536,K=1024] @ We[K=1024,N=512], bf16 MFMA.
// R4: the R3 post-mortem showed __syncthreads() drains vmcnt(0) at every
//     phase (HIP fence semantics), collapsing the 3-deep A / 2-deep B
//     prefetch pipeline -> latency-bound at MfmaUtil 12.8%.
//     Now: raw s_barrier + own-wave lgkmcnt(0) only (T3/T4 pattern);
//     counted vmcnt waits stay at use sites, loads ride across barriers.
//     Plus XOR-swizzled A-tile LDS (kills the 4-way q-group conflict on
//     both ds_write_b128 and ds_read_b128).
// ---------------------------------------------------------------------------

typedef float  floatx4 __attribute__((ext_vector_type(4)));
typedef __bf16 bf16x8  __attribute__((ext_vector_type(8)));
typedef short  short8  __attribute__((ext_vector_type(8)));

union bfu { bf16x8 v; short8 s; };

#define LOG2E_X2 2.8853900817779268f

// raw barrier: wait own LDS ops (write visibility / read WAR), do NOT
// drain vmcnt -- global prefetches stay in flight across the barrier.
#define BAR()                                              \
  do {                                                     \
    asm volatile("s_waitcnt lgkmcnt(0)" ::: "memory");     \
    __builtin_amdgcn_sched_barrier(0);                     \
    __builtin_amdgcn_s_barrier();                          \
    __builtin_amdgcn_sched_barrier(0);                     \
  } while (0)

// ---- kernel 0: W[512:1536,:] -> bf16 transposed Wt[n][k], LDS-tiled 64x64.
__global__ void wt_convert(const float* __restrict__ W, __bf16* __restrict__ Wt) {
  __shared__ float tile[64][65];                 // +1 pad: conflict-free both ways
  const int kt = blockIdx.x >> 3;                // 16 k-tiles
  const int nt = blockIdx.x & 7;                 // 8 n-tiles
  const int c  = threadIdx.x & 63;
  const int r4 = threadIdx.x >> 6;               // 4 rows per pass
  #pragma unroll 4
  for (int i = 0; i < 16; i++) {
    int r = i * 4 + r4;                          // k-local
    tile[r][c] = W[(long)(512 + kt * 64 + r) * 512 + nt * 64 + c];
  }
  __syncthreads();
  #pragma unroll 4
  for (int i = 0; i < 16; i++) {
    int n = i * 4 + r4;                          // n-local; lane c = k-local
    Wt[(long)(nt * 64 + n) * 1024 + kt * 64 + c] = (__bf16)tile[c][n];
  }
}

// ---- kernel 1: hproj[b][n] = bias[n] + sum_k hidden[b,k] * W[k,n]  (k<512)
__global__ void hproj_kernel(const float* __restrict__ hidden,
                             const float* __restrict__ W,
                             const float* __restrict__ bias,
                             float* __restrict__ hproj) {
  const int tid = threadIdx.x;            // n
  const int b_  = blockIdx.x >> 2;
  const int kc  = blockIdx.x & 3;
  __shared__ float hid[128];
  if (tid < 128) hid[tid] = hidden[b_ * 512 + kc * 128 + tid];
  __syncthreads();
  float acc = (kc == 0) ? bias[tid] : 0.f;
  const float* Wp = W + (long)(kc * 128) * 512 + tid;
  #pragma unroll 8
  for (int k = 0; k < 128; k++) acc = fmaf(hid[k], Wp[(long)k * 512], acc);
  atomicAdd(&hproj[b_ * 512 + tid], acc);
}

// ---- kernel 2: the big GEMM + tanh/v-dot epilogue, reg-staged pipeline
__global__ __launch_bounds__(256, 2) void gemm_score(
    const float* __restrict__ enc,    // [65536][1024] fp32
    const __bf16* __restrict__ Wt,    // [512][1024] bf16 (n-major)
    const float* __restrict__ hproj,  // [64][512]
    const float* __restrict__ v,      // [512]
    float* __restrict__ scores)       // [64][1024]  ([b][s])
{
  // bf16 A tile, double buffered. elem (c,m,j), c=k/8 in 0..3, m row, j=k%8:
  //   elem addr = c*512 + (m*8 ^ c*16) + j      (XOR = bank swizzle)
  // swizzle spreads the 4 q-groups across bank quads: both ds_write_b128
  // and ds_read_b128 hit the 8-cycle structural minimum.
  __shared__ __bf16 ldsA[2][2048];
  __shared__ float bscore[64];

  const int tid  = threadIdx.x;
  const int lane = tid & 63;
  const int wv   = tid >> 6;      // wave -> n-range [wv*128, wv*128+128)
  const int q    = lane >> 4;
  const int t    = lane & 15;
  const long m0  = (long)blockIdx.x * 64;

  // staging coords: thread -> row sm = tid>>2, k-chunk sf = tid&3; 32B/thread
  const int sm = tid >> 2;
  const int sf = tid & 3;
  const float* ap = enc + (m0 + sm) * 1024 + sf * 8;
  __bf16* aw0 = &ldsA[0][sf * 512 + ((sm * 8) ^ (sf * 16))];   // ds_write_b128
  __bf16* aw1 = &ldsA[1][sf * 512 + ((sm * 8) ^ (sf * 16))];

  // fragment read base: lane (q,t) rt -> A[rt*16+t][q*8 .. q*8+7]
  // addr = q*512 + rt*128 + (t*8 ^ q*16); rt*128 is in bits>=7, XOR in 4-5.
  const __bf16* ar0 = &ldsA[0][q * 512 + ((t * 8) ^ (q * 16))];
  const __bf16* ar1 = &ldsA[1][q * 512 + ((t * 8) ^ (q * 16))];

  // per-lane B base: Wt[n = wv*128 + ct*16 + t][k0 + q*8 ...], 16B per load
  const __bf16* bp = Wt + (long)(wv * 128 + t) * 1024 + q * 8;

  if (tid < 64) bscore[tid] = 0.f;

  floatx4 acc[4][8];
  #pragma unroll
  for (int i = 0; i < 4; i++)
    #pragma unroll
    for (int j = 0; j < 8; j++)
      acc[i][j] = (floatx4){0.f, 0.f, 0.f, 0.f};

  floatx4 ra[3][2];    // A staging regs: 3 k-steps in flight
  short8  bfr[2][8];   // B fragments, double buffered

  auto issueA = [&](int T, int s) {          // global fp32 -> regs (no wait)
    const float* p = ap + T * 32;
    ra[s][0] = *(const floatx4*)(p);
    ra[s][1] = *(const floatx4*)(p + 4);
  };
  auto writeA = [&](int s, __bf16* dst) {    // cvt once + 16B ds_write
    union bfu u;
    #pragma unroll
    for (int j = 0; j < 4; j++) {
      u.v[j]     = (__bf16)ra[s][0][j];
      u.v[4 + j] = (__bf16)ra[s][1][j];
    }
    *(bf16x8*)dst = u.v;
  };
  auto loadB = [&](int T, int s) {
    #pragma unroll
    for (int ct = 0; ct < 8; ct++) {
      union bfu u;
      u.v = *(const bf16x8*)(bp + T * 32 + (long)ct * 16 * 1024);
      bfr[s][ct] = u.s;
    }
  };
  auto compute = [&](const __bf16* base, int bs) {
    #pragma unroll
    for (int rt = 0; rt < 4; rt++) {
      union bfu u;
      u.v = *(const bf16x8*)(base + rt * 128);   // 1 ds_read_b128 per rt
      #pragma unroll
      for (int ct = 0; ct < 8; ct++)
        acc[rt][ct] = __builtin_amdgcn_mfma_f32_16x16x32_bf16(
            u.s, bfr[bs][ct], acc[rt][ct], 0, 0, 0);
    }
  };

  // prologue: A0..A2 in flight, B0/B1 in flight, stage A0 into buf0
  issueA(0, 0); issueA(1, 1); issueA(2, 2);
  loadB(0, 0);  loadB(1, 1);
  writeA(0, aw0);               // compiler waits vmcnt for A0 only
  BAR();

  // Phase T: compute A(T) from buf(T&1) with B(T)=bfr[T&1];
  //   issue A(T+3) into set T%3; cvt+write A(T+1) (loaded 2 phases ago ->
  //   vmcnt wait covered by ~2 phases of compute); reload B(T+2) after its
  //   set was consumed. Raw barrier: only lgkm drained -> A/B global loads
  //   stay in flight across phases.
#define PHASE(T, SI, SW)                                   \
  {                                                        \
    if ((T) < 29) issueA((T) + 3, SI);                     \
    if ((T) < 31) writeA(SW, ((T) & 1) ? aw0 : aw1);       \
    compute(((T) & 1) ? ar1 : ar0, (T) & 1);               \
    if ((T) < 30) loadB((T) + 2, (T) & 1);                 \
    BAR();                                                 \
  }

  PHASE(0, 0, 1)  PHASE(1, 1, 2)  PHASE(2, 2, 0)  PHASE(3, 0, 1)
  PHASE(4, 1, 2)  PHASE(5, 2, 0)  PHASE(6, 0, 1)  PHASE(7, 1, 2)
  PHASE(8, 2, 0)  PHASE(9, 0, 1)  PHASE(10, 1, 2) PHASE(11, 2, 0)
  PHASE(12, 0, 1) PHASE(13, 1, 2) PHASE(14, 2, 0) PHASE(15, 0, 1)
  PHASE(16, 1, 2) PHASE(17, 2, 0) PHASE(18, 0, 1) PHASE(19, 1, 2)
  PHASE(20, 2, 0) PHASE(21, 0, 1) PHASE(22, 1, 2) PHASE(23, 2, 0)
  PHASE(24, 0, 1) PHASE(25, 1, 2) PHASE(26, 2, 0) PHASE(27, 0, 1)
  PHASE(28, 1, 2) PHASE(29, 2, 0) PHASE(30, 0, 1) PHASE(31, 1, 2)
#undef PHASE

  // ---- epilogue: score[row] = sum_n v[n] * tanh(acc + hproj[row][n])
  float vv[8];
  #pragma unroll
  for (int ct = 0; ct < 8; ct++) vv[ct] = v[wv * 128 + ct * 16 + t];

  #pragma unroll
  for (int rt = 0; rt < 4; rt++) {
    #pragma unroll
    for (int r = 0; r < 4; r++) {
      int row = rt * 16 + q * 4 + r;              // C/D: row=(lane>>4)*4+reg
      const float* hrow = hproj + row * 512 + wv * 128 + t;
      float s = 0.f;
      #pragma unroll
      for (int ct = 0; ct < 8; ct++) {
        float e  = acc[rt][ct][r] + hrow[ct * 16];
        float ex = __builtin_amdgcn_exp2f(e * LOG2E_X2);        // e^(2x)
        float th = 1.f - 2.f * __builtin_amdgcn_rcpf(ex + 1.f); // tanh(x)
        s = fmaf(vv[ct], th, s);
      }
      s += __shfl_xor(s, 1);
      s += __shfl_xor(s, 2);
      s += __shfl_xor(s, 4);
      s += __shfl_xor(s, 8);
      if (t == 0) atomicAdd(&bscore[row], s);
    }
  }
  __syncthreads();   // full sync fine here (once, end of kernel)
  if (tid < 64) scores[(long)tid * 1024 + blockIdx.x] = bscore[tid];
}

// ---- kernel 3: softmax over s for each b
__global__ void softmax_kernel(const float* __restrict__ scores,
                               float* __restrict__ out) {
  const int b_   = blockIdx.x;
  const int tid  = threadIdx.x;
  const int lane = tid & 63;
  const int wv   = tid >> 6;
  __shared__ float redmax[4], redsum[4];

  float x[4];
  #pragma unroll
  for (int i = 0; i < 4; i++) x[i] = scores[b_ * 1024 + i * 256 + tid];
  float mx = fmaxf(fmaxf(x[0], x[1]), fmaxf(x[2], x[3]));
  #pragma unroll
  for (int off = 1; off < 64; off <<= 1) mx = fmaxf(mx, __shfl_xor(mx, off));
  if (lane == 0) redmax[wv] = mx;
  __syncthreads();
  mx = fmaxf(fmaxf(redmax[0], redmax[1]), fmaxf(redmax[2], redmax[3]));

  float e[4], s = 0.f;
  #pragma unroll
  for (int i = 0; i < 4; i++) { e[i] = __expf(x[i] - mx); s += e[i]; }
  #pragma unroll
  for (int off = 1; off < 64; off <<= 1) s += __shfl_xor(s, off);
  if (lane == 0) redsum[wv] = s;
  __syncthreads();
  s = redsum[0] + redsum[1] + redsum[2] + redsum[3];
  float inv = 1.f / s;
  #pragma unroll
  for (int i = 0; i < 4; i++) out[b_ * 1024 + i * 256 + tid] = e[i] * inv;
}

extern "C" void kernel_launch(void* const* d_in, const int* in_sizes, int n_in,
                              void* d_out, int out_size, void* d_ws, size_t ws_size,
                              hipStream_t stream) {
  (void)in_sizes; (void)n_in; (void)out_size; (void)ws_size;
  const float* hidden = (const float*)d_in[0];   // [64,512]
  const float* enc    = (const float*)d_in[1];   // [1024,64,1024]
  const float* W      = (const float*)d_in[2];   // [1536,512]
  const float* bias   = (const float*)d_in[3];   // [512]
  const float* v      = (const float*)d_in[4];   // [512]
  float* out = (float*)d_out;                    // [64,1024]

  char* ws = (char*)d_ws;
  __bf16* Wt    = (__bf16*)ws;                            // 1 MB
  float*  hproj = (float*)(ws + (1 << 20));               // 128 KB
  float*  scores= (float*)(ws + (1 << 20) + (128 << 10)); // 256 KB

  hipMemsetAsync(hproj, 0, 64 * 512 * sizeof(float), stream);
  wt_convert<<<128, 256, 0, stream>>>(W, Wt);
  hproj_kernel<<<256, 512, 0, stream>>>(hidden, W, bias, hproj);
  gemm_score<<<1024, 256, 0, stream>>>(enc, Wt, hproj, v, scores);
  softmax_kernel<<<64, 256, 0, stream>>>(scores, out);
}

// Round 3
// 417.319 us; speedup vs baseline: 1.1819x; 1.1239x over previous
//
#include <hip/hip_runtime.h>
#include <stdint.h>

// ---------------------------------------------------------------------------
// scores[b,s] = v . tanh( hidden[b] @ Wh + bias + enc[s,b] @ We )
// out[b,s]   = softmax_s(scores)
// Big GEMM: enc_flat[M=65536,K=1024] @ We[K=1024,N=512], bf16 MFMA.
// R5: R4 post-mortem — B-fragment loads were a 16-way gather (lanes 2KB
//     apart in n-major Wt): 16 transactions/instr x 8 instr/wave/phase
//     saturated the L1/TA path every phase. Fix: store B in MFMA-fragment
//     lane order ("packed B"): chunk ((T*4+wv)*8+ct)*64+lane, 16B/lane.
//     loadB is now 8 coalesced 1KB wave-loads per phase.
//     (Keeps R4's raw-barrier pipeline + XOR-swizzled A LDS, conflicts=0.)
// ---------------------------------------------------------------------------

typedef float  floatx4 __attribute__((ext_vector_type(4)));
typedef __bf16 bf16x8  __attribute__((ext_vector_type(8)));
typedef short  short8  __attribute__((ext_vector_type(8)));

union bfu { bf16x8 v; short8 s; };

#define LOG2E_X2 2.8853900817779268f

// raw barrier: wait own LDS ops only; global prefetches ride across.
#define BAR()                                              \
  do {                                                     \
    asm volatile("s_waitcnt lgkmcnt(0)" ::: "memory");     \
    __builtin_amdgcn_sched_barrier(0);                     \
    __builtin_amdgcn_s_barrier();                          \
    __builtin_amdgcn_sched_barrier(0);                     \
  } while (0)

// ---- kernel 0: W[512:1536,:] -> fragment-packed bf16 B.
// Bp element ((T*4+wv)*8+ct)*512 + (q*16+t)*8 + j  <-  W[512 + k][n]
//   where T=k>>5, q=(k>>3)&3, j=k&7, wv=n>>7, ct=(n>>4)&7, t=n&15.
__global__ void wt_convert(const float* __restrict__ W, __bf16* __restrict__ Bp) {
  __shared__ float tile[64][65];                 // +1 pad: conflict-free both ways
  const int kt = blockIdx.x >> 3;                // 16 k-tiles (64 k each)
  const int nt = blockIdx.x & 7;                 // 8 n-tiles (64 n each)
  const int c  = threadIdx.x & 63;
  const int r4 = threadIdx.x >> 6;               // 4 rows per pass
  #pragma unroll 4
  for (int i = 0; i < 16; i++) {
    int r = i * 4 + r4;                          // k-local
    tile[r][c] = W[(long)(512 + kt * 64 + r) * 512 + nt * 64 + c];
  }
  __syncthreads();
  // pack: 8 consecutive k -> one 16B chunk per thread
  const int n_loc = threadIdx.x & 63;
  const int kc4   = threadIdx.x >> 6;            // 0..3
  const int n_g   = nt * 64 + n_loc;
  const int wv    = n_g >> 7;
  const int ct    = (n_g >> 4) & 7;
  const int t     = n_g & 15;
  #pragma unroll
  for (int i = 0; i < 2; i++) {
    int chunk = i * 4 + kc4;                     // k_loc = chunk*8 + j
    int k_g   = kt * 64 + chunk * 8;
    int T     = k_g >> 5;
    int q     = (k_g >> 3) & 3;
    union bfu u;
    #pragma unroll
    for (int j = 0; j < 8; j++) u.v[j] = (__bf16)tile[chunk * 8 + j][n_loc];
    long cidx = ((long)(T * 4 + wv) * 8 + ct) * 64 + q * 16 + t;
    *(bf16x8*)(Bp + cidx * 8) = u.v;
  }
}

// ---- kernel 1: hproj[b][n] = bias[n] + sum_k hidden[b,k] * W[k,n]  (k<512)
__global__ void hproj_kernel(const float* __restrict__ hidden,
                             const float* __restrict__ W,
                             const float* __restrict__ bias,
                             float* __restrict__ hproj) {
  const int tid = threadIdx.x;            // n
  const int b_  = blockIdx.x >> 2;
  const int kc  = blockIdx.x & 3;
  __shared__ float hid[128];
  if (tid < 128) hid[tid] = hidden[b_ * 512 + kc * 128 + tid];
  __syncthreads();
  float acc = (kc == 0) ? bias[tid] : 0.f;
  const float* Wp = W + (long)(kc * 128) * 512 + tid;
  #pragma unroll 8
  for (int k = 0; k < 128; k++) acc = fmaf(hid[k], Wp[(long)k * 512], acc);
  atomicAdd(&hproj[b_ * 512 + tid], acc);
}

// ---- kernel 2: the big GEMM + tanh/v-dot epilogue, reg-staged pipeline
__global__ __launch_bounds__(256, 2) void gemm_score(
    const float* __restrict__ enc,    // [65536][1024] fp32
    const __bf16* __restrict__ Bp,    // packed B, 1 MB
    const float* __restrict__ hproj,  // [64][512]
    const float* __restrict__ v,      // [512]
    float* __restrict__ scores)       // [64][1024]  ([b][s])
{
  // bf16 A tile, double buffered. elem (c,m,j), c=k/8 in 0..3, m row, j=k%8:
  //   elem addr = c*512 + (m*8 ^ c*16) + j      (XOR = bank swizzle)
  __shared__ __bf16 ldsA[2][2048];
  __shared__ float bscore[64];

  const int tid  = threadIdx.x;
  const int lane = tid & 63;
  const int wv   = tid >> 6;      // wave -> n-range [wv*128, wv*128+128)
  const int q    = lane >> 4;
  const int t    = lane & 15;
  const long m0  = (long)blockIdx.x * 64;

  // staging coords: thread -> row sm = tid>>2, k-chunk sf = tid&3; 32B/thread
  const int sm = tid >> 2;
  const int sf = tid & 3;
  const float* ap = enc + (m0 + sm) * 1024 + sf * 8;
  __bf16* aw0 = &ldsA[0][sf * 512 + ((sm * 8) ^ (sf * 16))];   // ds_write_b128
  __bf16* aw1 = &ldsA[1][sf * 512 + ((sm * 8) ^ (sf * 16))];

  // fragment read base: lane (q,t) rt -> A[rt*16+t][q*8 .. q*8+7]
  const __bf16* ar0 = &ldsA[0][q * 512 + ((t * 8) ^ (q * 16))];
  const __bf16* ar1 = &ldsA[1][q * 512 + ((t * 8) ^ (q * 16))];

  // packed-B per-lane base: frag(T,ct) at + T*16384 + ct*512 elems
  const __bf16* bpb = Bp + ((long)wv * 512 + lane) * 8;

  if (tid < 64) bscore[tid] = 0.f;

  floatx4 acc[4][8];
  #pragma unroll
  for (int i = 0; i < 4; i++)
    #pragma unroll
    for (int j = 0; j < 8; j++)
      acc[i][j] = (floatx4){0.f, 0.f, 0.f, 0.f};

  floatx4 ra[3][2];    // A staging regs: 3 k-steps in flight
  short8  bfr[2][8];   // B fragments, double buffered

  auto issueA = [&](int T, int s) {          // global fp32 -> regs (no wait)
    const float* p = ap + T * 32;
    ra[s][0] = *(const floatx4*)(p);
    ra[s][1] = *(const floatx4*)(p + 4);
  };
  auto writeA = [&](int s, __bf16* dst) {    // cvt once + 16B ds_write
    union bfu u;
    #pragma unroll
    for (int j = 0; j < 4; j++) {
      u.v[j]     = (__bf16)ra[s][0][j];
      u.v[4 + j] = (__bf16)ra[s][1][j];
    }
    *(bf16x8*)dst = u.v;
  };
  auto loadB = [&](int T, int s) {           // 8 coalesced 1KB wave-loads
    #pragma unroll
    for (int ct = 0; ct < 8; ct++) {
      union bfu u;
      u.v = *(const bf16x8*)(bpb + (long)T * 16384 + ct * 512);
      bfr[s][ct] = u.s;
    }
  };
  auto compute = [&](const __bf16* base, int bs) {
    #pragma unroll
    for (int rt = 0; rt < 4; rt++) {
      union bfu u;
      u.v = *(const bf16x8*)(base + rt * 128);   // 1 ds_read_b128 per rt
      #pragma unroll
      for (int ct = 0; ct < 8; ct++)
        acc[rt][ct] = __builtin_amdgcn_mfma_f32_16x16x32_bf16(
            u.s, bfr[bs][ct], acc[rt][ct], 0, 0, 0);
    }
  };

  // prologue: A0..A2 in flight, B0/B1 in flight, stage A0 into buf0
  issueA(0, 0); issueA(1, 1); issueA(2, 2);
  loadB(0, 0);  loadB(1, 1);
  writeA(0, aw0);               // compiler waits vmcnt for A0 only
  BAR();

  // Phase T: compute A(T) from buf(T&1) with B(T)=bfr[T&1];
  //   issue A(T+3); cvt+write A(T+1) (loaded 2 phases ago); reload B(T+2).
  //   Raw barrier: only lgkm drained -> global loads ride across phases.
#define PHASE(T, SI, SW)                                   \
  {                                                        \
    if ((T) < 29) issueA((T) + 3, SI);                     \
    if ((T) < 31) writeA(SW, ((T) & 1) ? aw0 : aw1);       \
    compute(((T) & 1) ? ar1 : ar0, (T) & 1);               \
    if ((T) < 30) loadB((T) + 2, (T) & 1);                 \
    BAR();                                                 \
  }

  PHASE(0, 0, 1)  PHASE(1, 1, 2)  PHASE(2, 2, 0)  PHASE(3, 0, 1)
  PHASE(4, 1, 2)  PHASE(5, 2, 0)  PHASE(6, 0, 1)  PHASE(7, 1, 2)
  PHASE(8, 2, 0)  PHASE(9, 0, 1)  PHASE(10, 1, 2) PHASE(11, 2, 0)
  PHASE(12, 0, 1) PHASE(13, 1, 2) PHASE(14, 2, 0) PHASE(15, 0, 1)
  PHASE(16, 1, 2) PHASE(17, 2, 0) PHASE(18, 0, 1) PHASE(19, 1, 2)
  PHASE(20, 2, 0) PHASE(21, 0, 1) PHASE(22, 1, 2) PHASE(23, 2, 0)
  PHASE(24, 0, 1) PHASE(25, 1, 2) PHASE(26, 2, 0) PHASE(27, 0, 1)
  PHASE(28, 1, 2) PHASE(29, 2, 0) PHASE(30, 0, 1) PHASE(31, 1, 2)
#undef PHASE

  // ---- epilogue: score[row] = sum_n v[n] * tanh(acc + hproj[row][n])
  float vv[8];
  #pragma unroll
  for (int ct = 0; ct < 8; ct++) vv[ct] = v[wv * 128 + ct * 16 + t];

  #pragma unroll
  for (int rt = 0; rt < 4; rt++) {
    #pragma unroll
    for (int r = 0; r < 4; r++) {
      int row = rt * 16 + q * 4 + r;              // C/D: row=(lane>>4)*4+reg
      const float* hrow = hproj + row * 512 + wv * 128 + t;
      float s = 0.f;
      #pragma unroll
      for (int ct = 0; ct < 8; ct++) {
        float e  = acc[rt][ct][r] + hrow[ct * 16];
        float ex = __builtin_amdgcn_exp2f(e * LOG2E_X2);        // e^(2x)
        float th = 1.f - 2.f * __builtin_amdgcn_rcpf(ex + 1.f); // tanh(x)
        s = fmaf(vv[ct], th, s);
      }
      s += __shfl_xor(s, 1);
      s += __shfl_xor(s, 2);
      s += __shfl_xor(s, 4);
      s += __shfl_xor(s, 8);
      if (t == 0) atomicAdd(&bscore[row], s);
    }
  }
  __syncthreads();   // full sync fine here (once, end of kernel)
  if (tid < 64) scores[(long)tid * 1024 + blockIdx.x] = bscore[tid];
}

// ---- kernel 3: softmax over s for each b
__global__ void softmax_kernel(const float* __restrict__ scores,
                               float* __restrict__ out) {
  const int b_   = blockIdx.x;
  const int tid  = threadIdx.x;
  const int lane = tid & 63;
  const int wv   = tid >> 6;
  __shared__ float redmax[4], redsum[4];

  float x[4];
  #pragma unroll
  for (int i = 0; i < 4; i++) x[i] = scores[b_ * 1024 + i * 256 + tid];
  float mx = fmaxf(fmaxf(x[0], x[1]), fmaxf(x[2], x[3]));
  #pragma unroll
  for (int off = 1; off < 64; off <<= 1) mx = fmaxf(mx, __shfl_xor(mx, off));
  if (lane == 0) redmax[wv] = mx;
  __syncthreads();
  mx = fmaxf(fmaxf(redmax[0], redmax[1]), fmaxf(redmax[2], redmax[3]));

  float e[4], s = 0.f;
  #pragma unroll
  for (int i = 0; i < 4; i++) { e[i] = __expf(x[i] - mx); s += e[i]; }
  #pragma unroll
  for (int off = 1; off < 64; off <<= 1) s += __shfl_xor(s, off);
  if (lane == 0) redsum[wv] = s;
  __syncthreads();
  s = redsum[0] + redsum[1] + redsum[2] + redsum[3];
  float inv = 1.f / s;
  #pragma unroll
  for (int i = 0; i < 4; i++) out[b_ * 1024 + i * 256 + tid] = e[i] * inv;
}

extern "C" void kernel_launch(void* const* d_in, const int* in_sizes, int n_in,
                              void* d_out, int out_size, void* d_ws, size_t ws_size,
                              hipStream_t stream) {
  (void)in_sizes; (void)n_in; (void)out_size; (void)ws_size;
  const float* hidden = (const float*)d_in[0];   // [64,512]
  const float* enc    = (const float*)d_in[1];   // [1024,64,1024]
  const float* W      = (const float*)d_in[2];   // [1536,512]
  const float* bias   = (const float*)d_in[3];   // [512]
  const float* v      = (const float*)d_in[4];   // [512]
  float* out = (float*)d_out;                    // [64,1024]

  char* ws = (char*)d_ws;
  __bf16* Bp    = (__bf16*)ws;                            // 1 MB (packed B)
  float*  hproj = (float*)(ws + (1 << 20));               // 128 KB
  float*  scores= (float*)(ws + (1 << 20) + (128 << 10)); // 256 KB

  hipMemsetAsync(hproj, 0, 64 * 512 * sizeof(float), stream);
  wt_convert<<<128, 256, 0, stream>>>(W, Bp);
  hproj_kernel<<<256, 512, 0, stream>>>(hidden, W, bias, hproj);
  gemm_score<<<1024, 256, 0, stream>>>(enc, Bp, hproj, v, scores);
  softmax_kernel<<<64, 256, 0, stream>>>(scores, out);
}